// Round 4
// baseline (1075.549 us; speedup 1.0000x reference)
//
#include <hip/hip_runtime.h>

using u16 = unsigned short;
using u32 = unsigned int;

// ---------- bf16 helpers ----------
__device__ __forceinline__ float bf2f(u16 u) {
  union { u32 i; float f; } v; v.i = ((u32)u) << 16; return v.f;
}
__device__ __forceinline__ u16 f2bf(float f) {
  union { float f; u32 i; } v; v.f = f;
  u32 x = v.i;
  return (u16)((x + 0x7fffu + ((x >> 16) & 1u)) >> 16);  // RNE
}
__device__ __forceinline__ void bf8_to_f32(uint4 u, float* f) {
  f[0] = bf2f((u16)(u.x & 0xffff)); f[1] = bf2f((u16)(u.x >> 16));
  f[2] = bf2f((u16)(u.y & 0xffff)); f[3] = bf2f((u16)(u.y >> 16));
  f[4] = bf2f((u16)(u.z & 0xffff)); f[5] = bf2f((u16)(u.z >> 16));
  f[6] = bf2f((u16)(u.w & 0xffff)); f[7] = bf2f((u16)(u.w >> 16));
}
__device__ __forceinline__ uint4 f32_to_bf8(const float* f) {
  uint4 u;
  u.x = (u32)f2bf(f[0]) | ((u32)f2bf(f[1]) << 16);
  u.y = (u32)f2bf(f[2]) | ((u32)f2bf(f[3]) << 16);
  u.z = (u32)f2bf(f[4]) | ((u32)f2bf(f[5]) << 16);
  u.w = (u32)f2bf(f[6]) | ((u32)f2bf(f[7]) << 16);
  return u;
}

// ---------- problem constants ----------
// B=16, N=1024 (32x32), C=512, NH=8, D=64, QKV width 1536
// qkv col layout per head h: q at h*192+d, k at h*192+64+d, v at h*192+128+d
// DTYPES (established r0-r3): ALL inputs fp32, output fp32.
// Intermediates bf16 in ws (err ~0.03 << 0.108 threshold).
#define SCALE 0.125f

// ============================================================
// Kernel 1: QKV = X(16384x512 f32) @ Wqkv(512x1536 f32) + b -> bf16 ws
// 128x128 tile, BK=16, 8x8 micro-tile, fp32 accumulate
// ============================================================
__global__ __launch_bounds__(256) void qkv_gemm(
    const float* __restrict__ X, const float* __restrict__ W,
    const float* __restrict__ Bias, u16* __restrict__ QKV)
{
  __shared__ float As[16][136];  // [k][m]
  __shared__ float Bs[16][136];  // [k][n]
  const int t  = threadIdx.x;
  const int bm = blockIdx.y * 128;
  const int bn = blockIdx.x * 128;
  const int tm = (t >> 4) * 8;
  const int tn = (t & 15) * 8;
  const int lr = t >> 1;          // A-load row 0..127
  const int lc = (t & 1) * 8;     // A-load k-offset 0/8
  const int wk = t >> 4;          // B-load k row 0..15
  const int wn = (t & 15) * 8;    // B-load col
  float acc[8][8];
  #pragma unroll
  for (int i = 0; i < 8; i++)
    #pragma unroll
    for (int j = 0; j < 8; j++) acc[i][j] = 0.f;

  for (int k0 = 0; k0 < 512; k0 += 16) {
    float4 xa = *(const float4*)(X + (size_t)(bm + lr) * 512 + (k0 + lc));
    float4 xb = *(const float4*)(X + (size_t)(bm + lr) * 512 + (k0 + lc) + 4);
    float4 w0 = *(const float4*)(W + (size_t)(k0 + wk) * 1536 + (bn + wn));
    float4 w1 = *(const float4*)(W + (size_t)(k0 + wk) * 1536 + (bn + wn) + 4);
    As[lc + 0][lr] = xa.x; As[lc + 1][lr] = xa.y;
    As[lc + 2][lr] = xa.z; As[lc + 3][lr] = xa.w;
    As[lc + 4][lr] = xb.x; As[lc + 5][lr] = xb.y;
    As[lc + 6][lr] = xb.z; As[lc + 7][lr] = xb.w;
    *(float4*)&Bs[wk][wn]     = w0;
    *(float4*)&Bs[wk][wn + 4] = w1;
    __syncthreads();
    #pragma unroll
    for (int kk = 0; kk < 16; kk++) {
      float4 a0 = *(const float4*)&As[kk][tm];
      float4 a1 = *(const float4*)&As[kk][tm + 4];
      float4 b0 = *(const float4*)&Bs[kk][tn];
      float4 b1 = *(const float4*)&Bs[kk][tn + 4];
      float av[8] = {a0.x, a0.y, a0.z, a0.w, a1.x, a1.y, a1.z, a1.w};
      float bv[8] = {b0.x, b0.y, b0.z, b0.w, b1.x, b1.y, b1.z, b1.w};
      #pragma unroll
      for (int i = 0; i < 8; i++)
        #pragma unroll
        for (int j = 0; j < 8; j++) acc[i][j] += av[i] * bv[j];
    }
    __syncthreads();
  }
  float4 bb0 = *(const float4*)(Bias + bn + tn);
  float4 bb1 = *(const float4*)(Bias + bn + tn + 4);
  float bias[8] = {bb0.x, bb0.y, bb0.z, bb0.w, bb1.x, bb1.y, bb1.z, bb1.w};
  #pragma unroll
  for (int i = 0; i < 8; i++) {
    float v[8];
    #pragma unroll
    for (int j = 0; j < 8; j++) v[j] = acc[i][j] + bias[j];
    *(uint4*)(QKV + (size_t)(bm + tm + i) * 1536 + (bn + tn)) = f32_to_bf8(v);
  }
}

// ============================================================
// Kernel 2: flash attention per (b, h, 128-query block)
// QKV bf16 in; K-tiles of 128; LDS fp32 tiles; online softmax;
// P via LDS bf16 (aliases dead K tile); ATT out bf16.
// ============================================================
__global__ __launch_bounds__(256) void attn_kernel(
    const u16* __restrict__ QKV, u16* __restrict__ ATT)
{
  __shared__ float Qs[64][136];   // [d][q]
  __shared__ float Ks[64][136];   // [d][k]  (aliased by Ps after S-phase)
  __shared__ float Vs[128][72];   // [k][d]
  u16* Ps = (u16*)&Ks[0][0];      // [128][136] bf16, exactly fits Ks bytes

  const int t  = threadIdx.x;
  const int qt = blockIdx.x;      // 0..7  query tile
  const int h  = blockIdx.y;      // 0..7
  const int b  = blockIdx.z;      // 0..15
  const size_t base = (size_t)b * 1024 * 1536;
  const int tq = (t >> 4) * 8;    // 8 query rows per thread
  const int tk = (t & 15) * 8;    // 8 keys per thread (S-phase)
  const int td = (t & 15) * 4;    // 4 d-cols per thread (PV-phase)
  const int lj = t >> 1;          // load row 0..127
  const int ld = (t & 1) * 32;    // load d-offset 0/32

  // ---- load Q tile -> Qs[d][q] (transposed) ----
  {
    const u16* src = QKV + base + (size_t)(qt * 128 + lj) * 1536 + h * 192 + ld;
    #pragma unroll
    for (int c = 0; c < 4; c++) {
      uint4 u = *(const uint4*)(src + c * 8);
      float f[8]; bf8_to_f32(u, f);
      #pragma unroll
      for (int i = 0; i < 8; i++) Qs[ld + c * 8 + i][lj] = f[i];
    }
  }
  float m[8], l[8], O[8][4];
  #pragma unroll
  for (int i = 0; i < 8; i++) {
    m[i] = -1e30f; l[i] = 0.f;
    O[i][0] = O[i][1] = O[i][2] = O[i][3] = 0.f;
  }

  for (int kt = 0; kt < 8; kt++) {
    __syncthreads();  // Q visible (kt=0); P/V reads of prev tile done (kt>0)
    // ---- load K tile -> Ks[d][k], V tile -> Vs[k][d] ----
    {
      const u16* ksrc = QKV + base + (size_t)(kt * 128 + lj) * 1536 + h * 192 + 64 + ld;
      #pragma unroll
      for (int c = 0; c < 4; c++) {
        uint4 u = *(const uint4*)(ksrc + c * 8);
        float f[8]; bf8_to_f32(u, f);
        #pragma unroll
        for (int i = 0; i < 8; i++) Ks[ld + c * 8 + i][lj] = f[i];
      }
      const u16* vsrc = QKV + base + (size_t)(kt * 128 + lj) * 1536 + h * 192 + 128 + ld;
      #pragma unroll
      for (int c = 0; c < 4; c++) {
        uint4 u = *(const uint4*)(vsrc + c * 8);
        float f[8]; bf8_to_f32(u, f);
        *(float4*)&Vs[lj][ld + c * 8]     = make_float4(f[0], f[1], f[2], f[3]);
        *(float4*)&Vs[lj][ld + c * 8 + 4] = make_float4(f[4], f[5], f[6], f[7]);
      }
    }
    __syncthreads();
    // ---- S = Q·K^T (8x8 per thread) ----
    float s[8][8];
    #pragma unroll
    for (int i = 0; i < 8; i++)
      #pragma unroll
      for (int j = 0; j < 8; j++) s[i][j] = 0.f;
    #pragma unroll 4
    for (int d = 0; d < 64; d++) {
      float4 qa = *(const float4*)&Qs[d][tq];
      float4 qb = *(const float4*)&Qs[d][tq + 4];
      float4 ka = *(const float4*)&Ks[d][tk];
      float4 kb = *(const float4*)&Ks[d][tk + 4];
      float av[8] = {qa.x, qa.y, qa.z, qa.w, qb.x, qb.y, qb.z, qb.w};
      float bv[8] = {ka.x, ka.y, ka.z, ka.w, kb.x, kb.y, kb.z, kb.w};
      #pragma unroll
      for (int i = 0; i < 8; i++)
        #pragma unroll
        for (int j = 0; j < 8; j++) s[i][j] += av[i] * bv[j];
    }
    __syncthreads();  // K reads done -> safe to overwrite Ks with Ps
    // ---- online softmax (rows tq..tq+7; 16 lanes per row group) ----
    #pragma unroll
    for (int i = 0; i < 8; i++) {
      float mloc = -1e30f;
      #pragma unroll
      for (int j = 0; j < 8; j++) { s[i][j] *= SCALE; mloc = fmaxf(mloc, s[i][j]); }
      #pragma unroll
      for (int off = 8; off >= 1; off >>= 1) mloc = fmaxf(mloc, __shfl_xor(mloc, off));
      float mnew  = fmaxf(m[i], mloc);
      float alpha = __expf(m[i] - mnew);
      float rs = 0.f;
      #pragma unroll
      for (int j = 0; j < 8; j++) { float p = __expf(s[i][j] - mnew); s[i][j] = p; rs += p; }
      #pragma unroll
      for (int off = 8; off >= 1; off >>= 1) rs += __shfl_xor(rs, off);
      l[i] = l[i] * alpha + rs;
      m[i] = mnew;
      #pragma unroll
      for (int j = 0; j < 4; j++) O[i][j] *= alpha;
    }
    // ---- write P transposed: Ps[k][q], bf16 ----
    #pragma unroll
    for (int j = 0; j < 8; j++) {
      float col[8];
      #pragma unroll
      for (int i = 0; i < 8; i++) col[i] = s[i][j];
      *(uint4*)(Ps + (size_t)(tk + j) * 136 + tq) = f32_to_bf8(col);
    }
    __syncthreads();
    // ---- O += P·V ----
    #pragma unroll 4
    for (int k = 0; k < 128; k++) {
      uint4 pu  = *(const uint4*)(Ps + (size_t)k * 136 + tq);
      float4 v4 = *(const float4*)&Vs[k][td];
      float pf[8]; bf8_to_f32(pu, pf);
      #pragma unroll
      for (int i = 0; i < 8; i++) {
        O[i][0] += pf[i] * v4.x;
        O[i][1] += pf[i] * v4.y;
        O[i][2] += pf[i] * v4.z;
        O[i][3] += pf[i] * v4.w;
      }
    }
  }
  // ---- epilogue: normalize, write ATT[b*1024+q][h*64+d] bf16 ----
  #pragma unroll
  for (int i = 0; i < 8; i++) {
    float inv = 1.0f / l[i];
    u32 lo = (u32)f2bf(O[i][0] * inv) | ((u32)f2bf(O[i][1] * inv) << 16);
    u32 hi = (u32)f2bf(O[i][2] * inv) | ((u32)f2bf(O[i][3] * inv) << 16);
    *(uint2*)(ATT + (size_t)(b * 1024 + qt * 128 + tq + i) * 512 + h * 64 + td) =
        make_uint2(lo, hi);
  }
}

// ============================================================
// Kernel 3: OUT = ATT(16384x512 bf16) @ Wout(512x512 f32) + b(f32) + FT(f32) -> f32
// ============================================================
__global__ __launch_bounds__(256) void out_proj(
    const u16* __restrict__ A, const float* __restrict__ W,
    const float* __restrict__ Bias, const float* __restrict__ FT,
    float* __restrict__ OUT)
{
  __shared__ float As[16][136];
  __shared__ float Bs[16][136];
  const int t  = threadIdx.x;
  const int bm = blockIdx.y * 128;
  const int bn = blockIdx.x * 128;
  const int tm = (t >> 4) * 8;
  const int tn = (t & 15) * 8;
  const int lr = t >> 1;
  const int lc = (t & 1) * 8;
  const int wk = t >> 4;
  const int wn = (t & 15) * 8;
  float acc[8][8];
  #pragma unroll
  for (int i = 0; i < 8; i++)
    #pragma unroll
    for (int j = 0; j < 8; j++) acc[i][j] = 0.f;

  for (int k0 = 0; k0 < 512; k0 += 16) {
    uint4 xa = *(const uint4*)(A + (size_t)(bm + lr) * 512 + (k0 + lc));  // 8 bf16
    float xf[8]; bf8_to_f32(xa, xf);
    float4 w0 = *(const float4*)(W + (size_t)(k0 + wk) * 512 + (bn + wn));
    float4 w1 = *(const float4*)(W + (size_t)(k0 + wk) * 512 + (bn + wn) + 4);
    #pragma unroll
    for (int i = 0; i < 8; i++) As[lc + i][lr] = xf[i];
    *(float4*)&Bs[wk][wn]     = w0;
    *(float4*)&Bs[wk][wn + 4] = w1;
    __syncthreads();
    #pragma unroll
    for (int kk = 0; kk < 16; kk++) {
      float4 a0c = *(const float4*)&As[kk][tm];
      float4 a1c = *(const float4*)&As[kk][tm + 4];
      float4 b0c = *(const float4*)&Bs[kk][tn];
      float4 b1c = *(const float4*)&Bs[kk][tn + 4];
      float av[8] = {a0c.x, a0c.y, a0c.z, a0c.w, a1c.x, a1c.y, a1c.z, a1c.w};
      float bv[8] = {b0c.x, b0c.y, b0c.z, b0c.w, b1c.x, b1c.y, b1c.z, b1c.w};
      #pragma unroll
      for (int i = 0; i < 8; i++)
        #pragma unroll
        for (int j = 0; j < 8; j++) acc[i][j] += av[i] * bv[j];
    }
    __syncthreads();
  }
  float4 bb0 = *(const float4*)(Bias + bn + tn);
  float4 bb1 = *(const float4*)(Bias + bn + tn + 4);
  float bias[8] = {bb0.x, bb0.y, bb0.z, bb0.w, bb1.x, bb1.y, bb1.z, bb1.w};
  #pragma unroll
  for (int i = 0; i < 8; i++) {
    float4 r0 = *(const float4*)(FT + (size_t)(bm + tm + i) * 512 + (bn + tn));
    float4 r1 = *(const float4*)(FT + (size_t)(bm + tm + i) * 512 + (bn + tn) + 4);
    float4 o0 = make_float4(acc[i][0] + bias[0] + r0.x, acc[i][1] + bias[1] + r0.y,
                            acc[i][2] + bias[2] + r0.z, acc[i][3] + bias[3] + r0.w);
    float4 o1 = make_float4(acc[i][4] + bias[4] + r1.x, acc[i][5] + bias[5] + r1.y,
                            acc[i][6] + bias[6] + r1.z, acc[i][7] + bias[7] + r1.w);
    *(float4*)(OUT + (size_t)(bm + tm + i) * 512 + (bn + tn))     = o0;
    *(float4*)(OUT + (size_t)(bm + tm + i) * 512 + (bn + tn) + 4) = o1;
  }
}

// ============================================================
extern "C" void kernel_launch(void* const* d_in, const int* in_sizes, int n_in,
                              void* d_out, int out_size, void* d_ws, size_t ws_size,
                              hipStream_t stream) {
  const float* ft    = (const float*)d_in[0];  // [16][1024][512] f32
  const float* w_qkv = (const float*)d_in[1];  // [512][1536]   f32
  const float* b_qkv = (const float*)d_in[2];  // [1536]        f32
  const float* w_out = (const float*)d_in[3];  // [512][512]    f32
  const float* b_out = (const float*)d_in[4];  // [512]         f32
  float* out = (float*)d_out;                  // [16][1024][512] f32

  // workspace: qkv bf16 [16384][1536] (50.3 MB) + att bf16 [16384][512] (16.8 MB)
  u16* qkv = (u16*)d_ws;
  u16* att = (u16*)((char*)d_ws + (size_t)16384 * 1536 * 2);

  qkv_gemm   <<<dim3(12, 128), 256, 0, stream>>>(ft, w_qkv, b_qkv, qkv);
  attn_kernel<<<dim3(8, 8, 16), 256, 0, stream>>>(qkv, att);
  out_proj   <<<dim3(4, 128), 256, 0, stream>>>(att, w_out, b_out, ft, out);
}

// Round 5
// 366.714 us; speedup vs baseline: 2.9329x; 2.9329x over previous
//
#include <hip/hip_runtime.h>

using u16 = unsigned short;
using u32 = unsigned int;
typedef __attribute__((ext_vector_type(8))) short short8;  // 8 bf16 (4 VGPRs)
typedef __attribute__((ext_vector_type(4))) float f32x4;   // MFMA 16x16 C/D

#define MFMA16(A, B, C) __builtin_amdgcn_mfma_f32_16x16x32_bf16((A), (B), (C), 0, 0, 0)
#define SCALE 0.125f

// ---------- bf16 helpers ----------
__device__ __forceinline__ u16 f2bf(float f) {
  union { float f; u32 i; } v; v.f = f;
  u32 x = v.i;
  return (u16)((x + 0x7fffu + ((x >> 16) & 1u)) >> 16);  // RNE
}

// ============================================================
// Prep A: ft fp32 -> Xbf bf16 (16384x512)
// ============================================================
__global__ __launch_bounds__(256) void conv_x(const float* __restrict__ X,
                                              u16* __restrict__ Xbf) {
  const int i = (blockIdx.x * 256 + threadIdx.x) * 8;
  float4 a = *(const float4*)(X + i);
  float4 b = *(const float4*)(X + i + 4);
  float v[8] = {a.x, a.y, a.z, a.w, b.x, b.y, b.z, b.w};
  uint4 o;
  o.x = (u32)f2bf(v[0]) | ((u32)f2bf(v[1]) << 16);
  o.y = (u32)f2bf(v[2]) | ((u32)f2bf(v[3]) << 16);
  o.z = (u32)f2bf(v[4]) | ((u32)f2bf(v[5]) << 16);
  o.w = (u32)f2bf(v[6]) | ((u32)f2bf(v[7]) << 16);
  *(uint4*)(Xbf + i) = o;
}

// ============================================================
// Prep B: transpose+convert W[512][N] fp32 -> Wt[N][512] bf16
// z=0: w_qkv (N=1536), z=1: w_out (N=512)
// ============================================================
__global__ __launch_bounds__(256) void transpose_w(
    const float* __restrict__ Wq, const float* __restrict__ Wo,
    u16* __restrict__ Wqt, u16* __restrict__ Wot) {
  const int z = blockIdx.z;
  if (z == 1 && blockIdx.x >= 16) return;
  const float* src = z ? Wo : Wq;
  u16* dst = z ? Wot : Wqt;
  const int ncols = z ? 512 : 1536;
  __shared__ float tile[32][33];
  const int t = threadIdx.x;
  const int kt = blockIdx.y * 32, nt = blockIdx.x * 32;
  const int r = t >> 3, c4 = (t & 7) * 4;
  float4 v = *(const float4*)(src + (size_t)(kt + r) * ncols + nt + c4);
  tile[r][c4 + 0] = v.x; tile[r][c4 + 1] = v.y;
  tile[r][c4 + 2] = v.z; tile[r][c4 + 3] = v.w;
  __syncthreads();
  // write dst[n][k]: n = nt + r, k = kt + c4..c4+3
  u16 o0 = f2bf(tile[c4 + 0][r]), o1 = f2bf(tile[c4 + 1][r]);
  u16 o2 = f2bf(tile[c4 + 2][r]), o3 = f2bf(tile[c4 + 3][r]);
  uint2 p = make_uint2((u32)o0 | ((u32)o1 << 16), (u32)o2 | ((u32)o3 << 16));
  *(uint2*)(dst + (size_t)(nt + r) * 512 + kt + c4) = p;
}

// ============================================================
// Kernel 1: QKV GEMM (MFMA). C[16384][1536] = Xbf @ Wt^T + bias,
// scattered to Qp[b][h][n][64], Kp[b][h][n][64], Vt[b][h][64][n] (bf16).
// 128x128 tile, BK=32, 4 waves x (4x4) 16x16 tiles.
// ============================================================
__global__ __launch_bounds__(256) void qkv_gemm(
    const u16* __restrict__ Xbf, const u16* __restrict__ Wt,
    const float* __restrict__ Bias,
    u16* __restrict__ Qp, u16* __restrict__ Kp, u16* __restrict__ Vt) {
  __shared__ u16 Xs[128][40];  // [m][k] pad->80B rows (16B-aligned, 2-way banks)
  __shared__ u16 Ws[128][40];  // [n][k]
  const int t = threadIdx.x;
  const int bm = blockIdx.y * 128, bn = blockIdx.x * 128;
  const int w = t >> 6, lane = t & 63, quad = lane >> 4, l16 = lane & 15;
  const int mtb = (w >> 1) * 64, ntb = (w & 1) * 64;
  const int lr = t >> 1, lk = (t & 1) * 16;

  f32x4 acc[4][4];
  const f32x4 z4 = {0.f, 0.f, 0.f, 0.f};
  #pragma unroll
  for (int mi = 0; mi < 4; mi++)
    #pragma unroll
    for (int ni = 0; ni < 4; ni++) acc[mi][ni] = z4;

  for (int k0 = 0; k0 < 512; k0 += 32) {
    __syncthreads();
    *(uint4*)&Xs[lr][lk]     = *(const uint4*)(Xbf + (size_t)(bm + lr) * 512 + k0 + lk);
    *(uint4*)&Xs[lr][lk + 8] = *(const uint4*)(Xbf + (size_t)(bm + lr) * 512 + k0 + lk + 8);
    *(uint4*)&Ws[lr][lk]     = *(const uint4*)(Wt + (size_t)(bn + lr) * 512 + k0 + lk);
    *(uint4*)&Ws[lr][lk + 8] = *(const uint4*)(Wt + (size_t)(bn + lr) * 512 + k0 + lk + 8);
    __syncthreads();
    short8 af[4], bf[4];
    #pragma unroll
    for (int mi = 0; mi < 4; mi++)
      af[mi] = *(const short8*)&Xs[mtb + mi * 16 + l16][quad * 8];
    #pragma unroll
    for (int ni = 0; ni < 4; ni++)
      bf[ni] = *(const short8*)&Ws[ntb + ni * 16 + l16][quad * 8];
    #pragma unroll
    for (int mi = 0; mi < 4; mi++)
      #pragma unroll
      for (int ni = 0; ni < 4; ni++)
        acc[mi][ni] = MFMA16(af[mi], bf[ni], acc[mi][ni]);
  }

  // epilogue: C-layout (row=quad*4+r, col=l16) -> packed Q/K/V buffers
  #pragma unroll
  for (int ni = 0; ni < 4; ni++) {
    const int g = bn + ntb + ni * 16;        // global col of tile (uniform)
    const int h = g / 192, rr = g % 192;
    const int type = rr >> 6, dbase = rr & 63;
    const float bias = Bias[g + l16];
    #pragma unroll
    for (int mi = 0; mi < 4; mi++) {
      const int row0 = bm + mtb + mi * 16 + quad * 4;
      const int b = row0 >> 10, n0 = row0 & 1023;
      const size_t bh = (size_t)(b * 8 + h) * 65536;
      if (type == 2) {  // V -> Vt[b][h][d][n], 4 consecutive n pack to 8B
        u16 o[4];
        #pragma unroll
        for (int r = 0; r < 4; r++) o[r] = f2bf(acc[mi][ni][r] + bias);
        uint2 p = make_uint2((u32)o[0] | ((u32)o[1] << 16),
                             (u32)o[2] | ((u32)o[3] << 16));
        *(uint2*)(Vt + bh + (size_t)(dbase + l16) * 1024 + n0) = p;
      } else {
        u16* dst = (type ? Kp : Qp) + bh;
        #pragma unroll
        for (int r = 0; r < 4; r++)
          dst[(size_t)(n0 + r) * 64 + dbase + l16] = f2bf(acc[mi][ni][r] + bias);
      }
    }
  }
}

// ============================================================
// Kernel 2: flash attention (MFMA), per (qt, h, b) block, 4 waves.
// Q/K/V frags direct global->reg from packed buffers (L2-resident).
// LDS only for P (C-layout -> A-layout round-trip), per-wave rows,
// NO barriers. Online softmax in C-layout registers.
// ============================================================
__global__ __launch_bounds__(256) void attn_mfma(
    const u16* __restrict__ Qp, const u16* __restrict__ Kp,
    const u16* __restrict__ Vt, u16* __restrict__ ATT) {
  __shared__ u16 Ps[128][136];  // [q][key], stride 272B (16B-aligned, 2-way)
  const int t = threadIdx.x, w = t >> 6, lane = t & 63;
  const int quad = lane >> 4, l16 = lane & 15;
  const int qt = blockIdx.x, h = blockIdx.y, b = blockIdx.z;
  const size_t bh = (size_t)(b * 8 + h) * 65536;
  const u16* Qb = Qp + bh;  // [1024][64]
  const u16* Kb = Kp + bh;  // [1024][64]
  const u16* Vb = Vt + bh;  // [64][1024]

  // Q fragments (held in regs whole kernel): A[m=l16][k=quad*8+j]
  short8 qf[2][2];
  #pragma unroll
  for (int mi = 0; mi < 2; mi++)
    #pragma unroll
    for (int ks = 0; ks < 2; ks++)
      qf[mi][ks] = *(const short8*)(
          Qb + (size_t)(qt * 128 + w * 32 + mi * 16 + l16) * 64 + ks * 32 + quad * 8);

  float m_[2][4], l_[2][4];
  f32x4 Of[2][4];
  const f32x4 z4 = {0.f, 0.f, 0.f, 0.f};
  #pragma unroll
  for (int mi = 0; mi < 2; mi++) {
    #pragma unroll
    for (int r = 0; r < 4; r++) { m_[mi][r] = -1e30f; l_[mi][r] = 0.f; }
    #pragma unroll
    for (int ni = 0; ni < 4; ni++) Of[mi][ni] = z4;
  }

  for (int kt = 0; kt < 8; kt++) {
    // ---- S = Q K^T over 128 keys ----
    f32x4 s[2][8];
    #pragma unroll
    for (int mi = 0; mi < 2; mi++)
      #pragma unroll
      for (int nt = 0; nt < 8; nt++) s[mi][nt] = z4;
    #pragma unroll
    for (int nt = 0; nt < 8; nt++) {
      const u16* kp = Kb + (size_t)(kt * 128 + nt * 16 + l16) * 64 + quad * 8;
      short8 k0f = *(const short8*)(kp);
      short8 k1f = *(const short8*)(kp + 32);
      #pragma unroll
      for (int mi = 0; mi < 2; mi++) {
        s[mi][nt] = MFMA16(qf[mi][0], k0f, s[mi][nt]);
        s[mi][nt] = MFMA16(qf[mi][1], k1f, s[mi][nt]);
      }
    }
    // ---- online softmax (row = quad*4+r, key cols across 16-lane group) ----
    #pragma unroll
    for (int mi = 0; mi < 2; mi++)
      #pragma unroll
      for (int r = 0; r < 4; r++) {
        float mloc = -1e30f;
        #pragma unroll
        for (int nt = 0; nt < 8; nt++) mloc = fmaxf(mloc, s[mi][nt][r]);
        mloc *= SCALE;
        #pragma unroll
        for (int off = 8; off >= 1; off >>= 1)
          mloc = fmaxf(mloc, __shfl_xor(mloc, off));
        const float mnew = fmaxf(m_[mi][r], mloc);
        const float alpha = __expf(m_[mi][r] - mnew);
        float rs = 0.f;
        #pragma unroll
        for (int nt = 0; nt < 8; nt++) {
          float p = __expf(fmaf(s[mi][nt][r], SCALE, -mnew));
          s[mi][nt][r] = p; rs += p;
        }
        #pragma unroll
        for (int off = 8; off >= 1; off >>= 1) rs += __shfl_xor(rs, off);
        l_[mi][r] = l_[mi][r] * alpha + rs;
        m_[mi][r] = mnew;
        #pragma unroll
        for (int ni = 0; ni < 4; ni++) Of[mi][ni][r] *= alpha;
      }
    // ---- P: C-layout regs -> LDS (bf16), per-wave rows, no barrier ----
    #pragma unroll
    for (int mi = 0; mi < 2; mi++)
      #pragma unroll
      for (int nt = 0; nt < 8; nt++)
        #pragma unroll
        for (int r = 0; r < 4; r++)
          Ps[w * 32 + mi * 16 + quad * 4 + r][nt * 16 + l16] = f2bf(s[mi][nt][r]);
    // ---- O += P V ----
    #pragma unroll
    for (int ks = 0; ks < 4; ks++) {
      short8 pa[2];
      #pragma unroll
      for (int mi = 0; mi < 2; mi++)
        pa[mi] = *(const short8*)&Ps[w * 32 + mi * 16 + l16][ks * 32 + quad * 8];
      #pragma unroll
      for (int ni = 0; ni < 4; ni++) {
        short8 vf = *(const short8*)(
            Vb + (size_t)(ni * 16 + l16) * 1024 + kt * 128 + ks * 32 + quad * 8);
        #pragma unroll
        for (int mi = 0; mi < 2; mi++) Of[mi][ni] = MFMA16(pa[mi], vf, Of[mi][ni]);
      }
    }
  }
  // ---- epilogue: normalize, ATT[token][h*64+d] bf16 ----
  #pragma unroll
  for (int mi = 0; mi < 2; mi++)
    #pragma unroll
    for (int r = 0; r < 4; r++) {
      const float inv = 1.0f / l_[mi][r];
      const int row = b * 1024 + qt * 128 + w * 32 + mi * 16 + quad * 4 + r;
      #pragma unroll
      for (int ni = 0; ni < 4; ni++)
        ATT[(size_t)row * 512 + h * 64 + ni * 16 + l16] = f2bf(Of[mi][ni][r] * inv);
    }
}

// ============================================================
// Kernel 3: OUT = ATT(bf16) @ Wout^T + bias + ft (fp32) -> fp32
// Same GEMM skeleton as qkv_gemm.
// ============================================================
__global__ __launch_bounds__(256) void out_proj(
    const u16* __restrict__ A, const u16* __restrict__ Wt,
    const float* __restrict__ Bias, const float* __restrict__ FT,
    float* __restrict__ OUT) {
  __shared__ u16 As[128][40];
  __shared__ u16 Ws[128][40];
  const int t = threadIdx.x;
  const int bm = blockIdx.y * 128, bn = blockIdx.x * 128;
  const int w = t >> 6, lane = t & 63, quad = lane >> 4, l16 = lane & 15;
  const int mtb = (w >> 1) * 64, ntb = (w & 1) * 64;
  const int lr = t >> 1, lk = (t & 1) * 16;

  f32x4 acc[4][4];
  const f32x4 z4 = {0.f, 0.f, 0.f, 0.f};
  #pragma unroll
  for (int mi = 0; mi < 4; mi++)
    #pragma unroll
    for (int ni = 0; ni < 4; ni++) acc[mi][ni] = z4;

  for (int k0 = 0; k0 < 512; k0 += 32) {
    __syncthreads();
    *(uint4*)&As[lr][lk]     = *(const uint4*)(A + (size_t)(bm + lr) * 512 + k0 + lk);
    *(uint4*)&As[lr][lk + 8] = *(const uint4*)(A + (size_t)(bm + lr) * 512 + k0 + lk + 8);
    *(uint4*)&Ws[lr][lk]     = *(const uint4*)(Wt + (size_t)(bn + lr) * 512 + k0 + lk);
    *(uint4*)&Ws[lr][lk + 8] = *(const uint4*)(Wt + (size_t)(bn + lr) * 512 + k0 + lk + 8);
    __syncthreads();
    short8 af[4], bf[4];
    #pragma unroll
    for (int mi = 0; mi < 4; mi++)
      af[mi] = *(const short8*)&As[mtb + mi * 16 + l16][quad * 8];
    #pragma unroll
    for (int ni = 0; ni < 4; ni++)
      bf[ni] = *(const short8*)&Ws[ntb + ni * 16 + l16][quad * 8];
    #pragma unroll
    for (int mi = 0; mi < 4; mi++)
      #pragma unroll
      for (int ni = 0; ni < 4; ni++)
        acc[mi][ni] = MFMA16(af[mi], bf[ni], acc[mi][ni]);
  }

  #pragma unroll
  for (int ni = 0; ni < 4; ni++) {
    const int g = bn + ntb + ni * 16;
    const float bias = Bias[g + l16];
    #pragma unroll
    for (int mi = 0; mi < 4; mi++) {
      const int row0 = bm + mtb + mi * 16 + quad * 4;
      #pragma unroll
      for (int r = 0; r < 4; r++) {
        const size_t idx = (size_t)(row0 + r) * 512 + g + l16;
        OUT[idx] = acc[mi][ni][r] + bias + FT[idx];
      }
    }
  }
}

// ============================================================
extern "C" void kernel_launch(void* const* d_in, const int* in_sizes, int n_in,
                              void* d_out, int out_size, void* d_ws, size_t ws_size,
                              hipStream_t stream) {
  const float* ft    = (const float*)d_in[0];  // [16][1024][512] f32
  const float* w_qkv = (const float*)d_in[1];  // [512][1536]   f32
  const float* b_qkv = (const float*)d_in[2];  // [1536]        f32
  const float* w_out = (const float*)d_in[3];  // [512][512]    f32
  const float* b_out = (const float*)d_in[4];  // [512]         f32
  float* out = (float*)d_out;                  // [16][1024][512] f32

  // ws layout (bytes). Xbf region is reused as ATT after qkv_gemm finishes.
  char* p = (char*)d_ws;
  u16* Xbf    = (u16*)(p);                              // 16,777,216
  u16* ATT    = Xbf;                                    // alias (Xbf dead)
  u16* Wqkv_t = (u16*)(p + 16777216);                   //  1,572,864
  u16* Wout_t = (u16*)(p + 18350080);                   //    524,288
  u16* Qp     = (u16*)(p + 18874368);                   // 16,777,216
  u16* Kp     = (u16*)(p + 35651584);                   // 16,777,216
  u16* Vt     = (u16*)(p + 52428800);                   // 16,777,216 -> 69.2 MB

  conv_x     <<<4096, 256, 0, stream>>>(ft, Xbf);
  transpose_w<<<dim3(48, 16, 2), 256, 0, stream>>>(w_qkv, w_out, Wqkv_t, Wout_t);
  qkv_gemm   <<<dim3(12, 128), 256, 0, stream>>>(Xbf, Wqkv_t, b_qkv, Qp, Kp, Vt);
  attn_mfma  <<<dim3(8, 8, 16), 256, 0, stream>>>(Qp, Kp, Vt, ATT);
  out_proj   <<<dim3(4, 128), 256, 0, stream>>>(ATT, Wout_t, b_out, ft, out);
}